// Round 1
// baseline (63.255 us; speedup 1.0000x reference)
//
#include <hip/hip_runtime.h>

// Sizes are fixed by the reference: B=4, IN_C=64, IN_S=16384, OUT_C=64, OUT_S=4096, K=4.
// starts[s] = s*IN_S/OUT_S = 4*s exactly; idx = 4s+k, never clamped (max 16383).
//
// out[b,o,s] = bias[o,s] + sum_{i,k} x[b,i,4s+k] * w[i,k,o,s]
//
// Thread mapping: one s, one o-pair (o0,o0+1), all 4 batches -> 8 accumulators.
// - weights read exactly once, coalesced in s (dword/lane)
// - x read as one aligned float4 per (b,i) (16B/lane, coalesced)
// - grid: 16 s-tiles x 32 o-groups = 512 blocks; chunked XCD swizzle keeps each
//   s-tile's x slice (1 MB) resident in one XCD's L2 across its 32 o-group blocks.

#define IN_C_  64
#define OUT_S_LOG2 12   // 4096

__global__ __launch_bounds__(256) void adj1d_kernel(
    const float* __restrict__ x, const float* __restrict__ w,
    const float* __restrict__ bias, float* __restrict__ out) {

  int bid = blockIdx.x;                 // 0..511
  // chunked XCD swizzle: XCD = bid&7 gets 64 consecutive logical blocks
  // (= 2 s-tiles x all 32 o-groups) -> x slice L2-resident per XCD.
  int wgid = (bid & 7) * 64 + (bid >> 3);
  int og = wgid & 31;                   // o-group (2 output channels)
  int st = wgid >> 5;                   // s-tile (256 s values)
  int s  = (st << 8) + threadIdx.x;
  int o0 = og << 1;

  float acc00 = 0.f, acc01 = 0.f, acc02 = 0.f, acc03 = 0.f;  // o0,   b=0..3
  float acc10 = 0.f, acc11 = 0.f, acc12 = 0.f, acc13 = 0.f;  // o0+1, b=0..3

  const float4* __restrict__ xv = reinterpret_cast<const float4*>(x);
  // w element index: ((i*4+k)*64 + o)*4096 + s ; per-(i,k) stride = 262144 elems
  const float* __restrict__ wp0 = w + (o0 << OUT_S_LOG2) + s;

  #pragma unroll 2
  for (int i = 0; i < IN_C_; ++i) {
    float xa[4][4];  // [b][k]
    *reinterpret_cast<float4*>(xa[0]) = xv[((0 * IN_C_ + i) << 12) + s];
    *reinterpret_cast<float4*>(xa[1]) = xv[((1 * IN_C_ + i) << 12) + s];
    *reinterpret_cast<float4*>(xa[2]) = xv[((2 * IN_C_ + i) << 12) + s];
    *reinterpret_cast<float4*>(xa[3]) = xv[((3 * IN_C_ + i) << 12) + s];
    #pragma unroll
    for (int k = 0; k < 4; ++k) {
      const float* wp = wp0 + (size_t)(i * 4 + k) * 262144;
      float wa = wp[0];
      float wb = wp[4096];
      acc00 = fmaf(xa[0][k], wa, acc00);
      acc01 = fmaf(xa[1][k], wa, acc01);
      acc02 = fmaf(xa[2][k], wa, acc02);
      acc03 = fmaf(xa[3][k], wa, acc03);
      acc10 = fmaf(xa[0][k], wb, acc10);
      acc11 = fmaf(xa[1][k], wb, acc11);
      acc12 = fmaf(xa[2][k], wb, acc12);
      acc13 = fmaf(xa[3][k], wb, acc13);
    }
  }

  float bA = bias[(o0 << OUT_S_LOG2) + s];
  float bB = bias[((o0 + 1) << OUT_S_LOG2) + s];

  out[((0 * 64 + o0) << OUT_S_LOG2) + s]     = acc00 + bA;
  out[((1 * 64 + o0) << OUT_S_LOG2) + s]     = acc01 + bA;
  out[((2 * 64 + o0) << OUT_S_LOG2) + s]     = acc02 + bA;
  out[((3 * 64 + o0) << OUT_S_LOG2) + s]     = acc03 + bA;
  out[((0 * 64 + o0 + 1) << OUT_S_LOG2) + s] = acc10 + bB;
  out[((1 * 64 + o0 + 1) << OUT_S_LOG2) + s] = acc11 + bB;
  out[((2 * 64 + o0 + 1) << OUT_S_LOG2) + s] = acc12 + bB;
  out[((3 * 64 + o0 + 1) << OUT_S_LOG2) + s] = acc13 + bB;
}

extern "C" void kernel_launch(void* const* d_in, const int* in_sizes, int n_in,
                              void* d_out, int out_size, void* d_ws, size_t ws_size,
                              hipStream_t stream) {
  const float* x    = (const float*)d_in[0];  // (4, 64, 16384)
  const float* w    = (const float*)d_in[1];  // (64, 4, 64, 4096)
  const float* bias = (const float*)d_in[2];  // (64, 4096)
  float* out = (float*)d_out;                 // (4, 64, 4096)

  // 16 s-tiles x 32 o-groups = 512 blocks, 256 threads each
  adj1d_kernel<<<512, 256, 0, stream>>>(x, w, bias, out);
}